// Round 8
// baseline (746.579 us; speedup 1.0000x reference)
//
#include <hip/hip_runtime.h>
#include <hip/hip_cooperative_groups.h>
#include <math.h>

namespace cg = cooperative_groups;

#define DEG_EPS 1e-12f
#define LN_EPS  1e-5f

typedef __attribute__((ext_vector_type(8))) short bf16x8;
typedef __attribute__((ext_vector_type(4))) float f32x4;

__device__ __forceinline__ short f2bf(float f) {      // fp32 -> bf16 RNE
    unsigned u = __float_as_uint(f);
    u += 0x7FFF + ((u >> 16) & 1);
    return (short)(u >> 16);
}

// ---------------------------------------------------------------------------
// ws layout (8-byte aligned first):
//   packed : N * 8       (bits [55:40] = edge count, bits [39:0] = sum(ew)*2^24)
//   meta   : E * 8       (int2 {col, bitcast(nw)})
//   xwb    : N * 64 * 2  (bf16 xw = x @ W^T)
//   ord    : E * 4       (within-row ordinal of each edge)
//   dis    : N * 4       (rsqrt(deg+eps))
//   rowptr : (N+1)*4
//   bsums  : NB * 4
//   boffs  : NB * 4
// ---------------------------------------------------------------------------

// One cooperative kernel: phases separated by grid.sync() — kills the ~90us
// of inter-dispatch overhead and the serial block-sum scan.
__global__ __launch_bounds__(256, 6) void k_mega(
    const float* __restrict__ x, const int* __restrict__ rows,
    const int* __restrict__ cols, const float* __restrict__ ew,
    const float* __restrict__ W, const float* __restrict__ bias,
    const float* __restrict__ gamma, const float* __restrict__ beta,
    float* __restrict__ out,
    unsigned long long* __restrict__ packed, int2* __restrict__ meta,
    unsigned short* __restrict__ xwb, unsigned* __restrict__ ord,
    float* __restrict__ dis, int* __restrict__ rowptr,
    int* __restrict__ bsums, int* __restrict__ boffs,
    int N, int E, int NB, int Ntiles)
{
    cg::grid_group grid = cg::this_grid();
    const int tid  = threadIdx.x;
    const int gtid = blockIdx.x * 256 + tid;
    const int gsz  = gridDim.x * 256;
    const int lane = tid & 63;
    const int wv   = tid >> 6;

    __shared__ int sc[256];

    // ---- phase 0: zero packed ----
    for (int i = gtid; i < N; i += gsz) packed[i] = 0ULL;
    grid.sync();

    // ---- phase 1: count + fixed-point deg; atomic return = ordinal ----
    for (int e = gtid; e < E; e += gsz) {
        int r = rows[e];
        unsigned long long fx = (unsigned long long)__float2uint_rn(ew[e] * 16777216.0f);
        unsigned long long old = atomicAdd(&packed[r], (1ULL << 40) | fx);
        ord[e] = (unsigned)(old >> 40);
    }
    grid.sync();

    // ---- phase 2a: per-1024-row block sums ----
    for (int b = blockIdx.x; b < NB; b += gridDim.x) {
        int base = b * 1024 + tid * 4;
        int s = 0;
#pragma unroll
        for (int k = 0; k < 4; ++k) {
            int i = base + k;
            if (i < N) s += (int)(packed[i] >> 40);
        }
        sc[tid] = s; __syncthreads();
        for (int off = 128; off > 0; off >>= 1) {
            if (tid < off) sc[tid] += sc[tid + off];
            __syncthreads();
        }
        if (tid == 0) bsums[b] = sc[0];
        __syncthreads();
    }
    grid.sync();

    // ---- phase 2b: parallel scan of block sums (block 0, 256 at a time) ----
    if (blockIdx.x == 0) {
        int carry = 0;
        for (int b0 = 0; b0 < NB; b0 += 256) {
            int idx = b0 + tid;
            int v = (idx < NB) ? bsums[idx] : 0;
            sc[tid] = v; __syncthreads();
            for (int off = 1; off < 256; off <<= 1) {
                int u = (tid >= off) ? sc[tid - off] : 0;
                __syncthreads();
                sc[tid] += u;
                __syncthreads();
            }
            if (idx < NB) boffs[idx] = carry + sc[tid] - v;
            int tot = sc[255];
            __syncthreads();
            carry += tot;
        }
        if (tid == 0) rowptr[N] = carry;   // == E
    }
    grid.sync();

    // ---- phase 2c: rowptr (exclusive) + dis = rsqrt(deg+eps) ----
    for (int b = blockIdx.x; b < NB; b += gridDim.x) {
        int base = b * 1024 + tid * 4;
        int c[4]; int s = 0;
#pragma unroll
        for (int k = 0; k < 4; ++k) {
            int i = base + k;
            unsigned long long p = (i < N) ? packed[i] : 0ULL;
            c[k] = (int)(p >> 40);
            s += c[k];
            if (i < N) {
                double deg = 1.0 + (double)(p & 0xFFFFFFFFFFULL) * (1.0 / 16777216.0);
                dis[i] = rsqrtf((float)deg + DEG_EPS);
            }
        }
        sc[tid] = s; __syncthreads();
        int my = s;
        for (int off = 1; off < 256; off <<= 1) {
            int u = (tid >= off) ? sc[tid - off] : 0;
            __syncthreads();
            sc[tid] += u;
            __syncthreads();
        }
        int run = sc[tid] - my + boffs[b];
#pragma unroll
        for (int k = 0; k < 4; ++k) {
            int i = base + k;
            if (i < N) rowptr[i] = run;
            run += c[k];
        }
        __syncthreads();
    }
    grid.sync();

    // ---- phase 3: fill CSR (first 2/3 of blocks) ∥ xw MFMA (last 1/3) ----
    {
        int xwB = gridDim.x / 3;
        int fillB = gridDim.x - xwB;
        if (blockIdx.x < fillB) {
            for (int e = blockIdx.x * 256 + tid; e < E; e += fillB * 256) {
                int r = rows[e], c = cols[e];
                float nw = ew[e] * dis[r] * dis[c];
                meta[rowptr[r] + (int)ord[e]] = make_int2(c, __float_as_int(nw));
            }
        } else {
            // xw = x @ W^T via mfma_f32_16x16x32_bf16: 16-node x 64-feat strip
            int wave = (blockIdx.x - fillB) * 4 + wv;
            int nwv = xwB * 4;
            int m = lane & 15, q = lane >> 4;
            for (int t = wave; t < Ntiles; t += nwv) {
                int n0 = t * 16;
                int nr = n0 + m; if (nr >= N) nr = N - 1;
                bf16x8 afrag[2];
#pragma unroll
                for (int s = 0; s < 2; ++s) {
                    const float4* xp = (const float4*)(x + (size_t)nr * 64 + s * 32 + q * 8);
                    float4 lo = xp[0], hi = xp[1];
                    bf16x8 v;
                    v[0] = f2bf(lo.x); v[1] = f2bf(lo.y); v[2] = f2bf(lo.z); v[3] = f2bf(lo.w);
                    v[4] = f2bf(hi.x); v[5] = f2bf(hi.y); v[6] = f2bf(hi.z); v[7] = f2bf(hi.w);
                    afrag[s] = v;
                }
#pragma unroll
                for (int f = 0; f < 4; ++f) {
                    f32x4 acc = {0.f, 0.f, 0.f, 0.f};
#pragma unroll
                    for (int s = 0; s < 2; ++s) {
                        const float4* wp = (const float4*)(W + (f * 16 + m) * 64 + s * 32 + q * 8);
                        float4 lo = wp[0], hi = wp[1];
                        bf16x8 bv;
                        bv[0] = f2bf(lo.x); bv[1] = f2bf(lo.y); bv[2] = f2bf(lo.z); bv[3] = f2bf(lo.w);
                        bv[4] = f2bf(hi.x); bv[5] = f2bf(hi.y); bv[6] = f2bf(hi.z); bv[7] = f2bf(hi.w);
                        acc = __builtin_amdgcn_mfma_f32_16x16x32_bf16(afrag[s], bv, acc, 0, 0, 0);
                    }
#pragma unroll
                    for (int r4 = 0; r4 < 4; ++r4) {
                        int node = n0 + q * 4 + r4;
                        if (node < N)
                            xwb[(size_t)node * 64 + f * 16 + m] = (unsigned short)f2bf(acc[r4]);
                    }
                }
            }
        }
    }
    grid.sync();

    // ---- phase 4: fused SpMM + bias + GELU + LayerNorm + residual ----
    {
        int wave = blockIdx.x * 4 + wv;
        int nwv = gridDim.x * 4;
        for (int row = wave; row < N; row += nwv) {
            float s = dis[row];   // wave-uniform
            float acc = __uint_as_float((unsigned)xwb[(size_t)row * 64 + lane] << 16) * (s * s);

            int start = rowptr[row], end = rowptr[row + 1];
            for (int base = start; base < end; base += 64) {
                int rem = end - base;
                int cnt = rem < 64 ? rem : 64;
                int2 mm = make_int2(0, 0);
                if (lane < rem) mm = meta[base + lane];
                int j = 0;
                for (; j + 4 <= cnt; j += 4) {
                    int   c0 = __shfl(mm.x, j + 0, 64);
                    float w0 = __int_as_float(__shfl(mm.y, j + 0, 64));
                    int   c1 = __shfl(mm.x, j + 1, 64);
                    float w1 = __int_as_float(__shfl(mm.y, j + 1, 64));
                    int   c2 = __shfl(mm.x, j + 2, 64);
                    float w2 = __int_as_float(__shfl(mm.y, j + 2, 64));
                    int   c3 = __shfl(mm.x, j + 3, 64);
                    float w3 = __int_as_float(__shfl(mm.y, j + 3, 64));
                    float v0 = __uint_as_float((unsigned)xwb[(size_t)c0 * 64 + lane] << 16);
                    float v1 = __uint_as_float((unsigned)xwb[(size_t)c1 * 64 + lane] << 16);
                    float v2 = __uint_as_float((unsigned)xwb[(size_t)c2 * 64 + lane] << 16);
                    float v3 = __uint_as_float((unsigned)xwb[(size_t)c3 * 64 + lane] << 16);
                    acc = fmaf(v0, w0, acc);
                    acc = fmaf(v1, w1, acc);
                    acc = fmaf(v2, w2, acc);
                    acc = fmaf(v3, w3, acc);
                }
                for (; j < cnt; ++j) {
                    int   c = __shfl(mm.x, j, 64);
                    float w = __int_as_float(__shfl(mm.y, j, 64));
                    acc = fmaf(__uint_as_float((unsigned)xwb[(size_t)c * 64 + lane] << 16),
                               w, acc);
                }
            }

            float a = acc + bias[lane];
            a = 0.5f * a * (1.0f + erff(a * 0.70710678118654752f));   // exact gelu

            float sum = a, ssq = a * a;
#pragma unroll
            for (int mk = 1; mk < 64; mk <<= 1) {
                sum += __shfl_xor(sum, mk, 64);
                ssq += __shfl_xor(ssq, mk, 64);
            }
            float mean = sum * (1.0f / 64.0f);
            float var  = fmaxf(ssq * (1.0f / 64.0f) - mean * mean, 0.0f);
            float rs   = rsqrtf(var + LN_EPS);

            out[(size_t)row * 64 + lane] =
                (a - mean) * rs * gamma[lane] + beta[lane] + x[(size_t)row * 64 + lane];
        }
    }
}

// ---------------------------------------------------------------------------
extern "C" void kernel_launch(void* const* d_in, const int* in_sizes, int n_in,
                              void* d_out, int out_size, void* d_ws, size_t ws_size,
                              hipStream_t stream) {
    const float* x   = (const float*)d_in[0];
    const int*   ei  = (const int*)  d_in[1];   // [2,E] flat: rows then cols
    const float* ew  = (const float*)d_in[2];
    const float* W   = (const float*)d_in[3];
    const float* b   = (const float*)d_in[4];
    const float* g   = (const float*)d_in[5];
    const float* bt  = (const float*)d_in[6];
    float* out = (float*)d_out;

    const int N = in_sizes[0] / 64;
    const int E = in_sizes[1] / 2;
    const int* rows = ei;
    const int* cols = ei + E;
    const int NB = (N + 1023) / 1024;
    const int Ntiles = (N + 15) / 16;

    // ws carve-up (8-byte aligned members first)
    char* w8 = (char*)d_ws;
    unsigned long long* packed = (unsigned long long*)w8; w8 += (size_t)N * 8;
    int2*           meta = (int2*)w8;                     w8 += (size_t)E * 8;
    unsigned short* xwb  = (unsigned short*)w8;           w8 += (size_t)N * 128;
    unsigned*       ord  = (unsigned*)w8;                 w8 += (size_t)E * 4;
    float*          dis  = (float*)w8;                    w8 += (size_t)N * 4;
    int*          rowptr = (int*)w8;                      w8 += (size_t)(N + 1) * 4;
    int*          bsums  = (int*)w8;                      w8 += (size_t)NB * 4;
    int*          boffs  = (int*)w8;

    // grid: guaranteed-co-resident block count for cooperative launch
    int bpc = 0;
    if (hipOccupancyMaxActiveBlocksPerMultiprocessor(&bpc, k_mega, 256, 0)
            != hipSuccess || bpc < 1)
        bpc = 2;
    int ncu = 256;
    hipDeviceProp_t prop;
    int dev = 0;
    if (hipGetDevice(&dev) == hipSuccess &&
        hipGetDeviceProperties(&prop, dev) == hipSuccess)
        ncu = prop.multiProcessorCount;
    long Gl = (long)bpc * ncu;
    if (Gl > 2048) Gl = 2048;
    if (Gl < NB) Gl = NB;          // phase 2a/2c single-pass assumption safety
    unsigned G = (unsigned)Gl;

    void* args[] = {
        (void*)&x, (void*)&rows, (void*)&cols, (void*)&ew, (void*)&W,
        (void*)&b, (void*)&g, (void*)&bt, (void*)&out,
        (void*)&packed, (void*)&meta, (void*)&xwb, (void*)&ord,
        (void*)&dis, (void*)&rowptr, (void*)&bsums, (void*)&boffs,
        (void*)&N, (void*)&E, (void*)&NB, (void*)&Ntiles
    };
    hipLaunchCooperativeKernel(k_mega, dim3(G), dim3(256), args, 0, stream);
}

// Round 9
// 217.785 us; speedup vs baseline: 3.4281x; 3.4281x over previous
//
#include <hip/hip_runtime.h>
#include <math.h>

#define DEG_EPS 1e-12f
#define LN_EPS  1e-5f

typedef __attribute__((ext_vector_type(8))) short bf16x8;
typedef __attribute__((ext_vector_type(4))) float f32x4;

__device__ __forceinline__ short f2bf(float f) {      // fp32 -> bf16 RNE
    unsigned u = __float_as_uint(f);
    u += 0x7FFF + ((u >> 16) & 1);
    return (short)(u >> 16);
}
__device__ __forceinline__ float bf_lo(unsigned u) { return __uint_as_float(u << 16); }
__device__ __forceinline__ float bf_hi(unsigned u) { return __uint_as_float(u & 0xFFFF0000u); }

// ---------------------------------------------------------------------------
// ws layout (8-byte aligned first):
//   packed : N * 8       (bits [55:40] = edge count, bits [39:0] = sum(ew)*2^24)
//   meta   : E * 8       (int2 {col, bitcast(nw)})
//   xwb    : N * 64 * 2  (bf16 xw = x @ W^T)
//   ord    : E * 4       (within-row ordinal of each edge)
//   dis    : N * 4       (rsqrt(deg+eps))
//   rowptr : (N+1)*4
//   bsums  : NB * 4
//   boffs  : NB * 4
// ---------------------------------------------------------------------------

// one 64-bit atomic per edge: count + fixed-point deg; return gives ordinal
__global__ __launch_bounds__(256) void k_count_deg(const int* __restrict__ rows,
                                                   const float* __restrict__ ew,
                                                   unsigned long long* __restrict__ packed,
                                                   unsigned* __restrict__ ord, int E) {
    int e = blockIdx.x * blockDim.x + threadIdx.x;
    if (e < E) {
        int r = rows[e];
        unsigned long long fx = (unsigned long long)__float2uint_rn(ew[e] * 16777216.0f);
        unsigned long long old = atomicAdd(&packed[r], (1ULL << 40) | fx);
        ord[e] = (unsigned)(old >> 40);
    }
}

// per-block (1024 rows) count reduction -> bsums
__global__ __launch_bounds__(256) void k_scan1(const unsigned long long* __restrict__ packed,
                                               int* __restrict__ bsums, int N) {
    __shared__ int sc[256];
    int t = threadIdx.x, b = blockIdx.x;
    int base = b * 1024 + t * 4;
    int s = 0;
#pragma unroll
    for (int k = 0; k < 4; ++k) {
        int i = base + k;
        if (i < N) s += (int)(packed[i] >> 40);
    }
    sc[t] = s; __syncthreads();
    for (int off = 128; off > 0; off >>= 1) {
        if (t < off) sc[t] += sc[t + off];
        __syncthreads();
    }
    if (t == 0) bsums[b] = sc[0];
}

// parallel exclusive scan of block sums — single block, Hillis-Steele
__global__ __launch_bounds__(256) void k_scan2(const int* __restrict__ bsums,
                                               int* __restrict__ boffs,
                                               int* __restrict__ rowptr, int NB, int N) {
    __shared__ int sc[256];
    int t = threadIdx.x;
    int carry = 0;
    for (int b0 = 0; b0 < NB; b0 += 256) {
        int idx = b0 + t;
        int v = (idx < NB) ? bsums[idx] : 0;
        sc[t] = v; __syncthreads();
        for (int off = 1; off < 256; off <<= 1) {
            int u = (t >= off) ? sc[t - off] : 0;
            __syncthreads();
            sc[t] += u;
            __syncthreads();
        }
        if (idx < NB) boffs[idx] = carry + sc[t] - v;
        int tot = sc[255];
        __syncthreads();
        carry += tot;
    }
    if (t == 0) rowptr[N] = carry;   // == E
}

// block scan -> rowptr (exclusive); dis = rsqrt(deg+eps) from packed low bits
__global__ __launch_bounds__(256) void k_scan3(const unsigned long long* __restrict__ packed,
                                               const int* __restrict__ boffs,
                                               int* __restrict__ rowptr,
                                               float* __restrict__ dis, int N) {
    __shared__ int sc[256];
    int t = threadIdx.x, b = blockIdx.x;
    int base = b * 1024 + t * 4;
    int c[4]; int s = 0;
#pragma unroll
    for (int k = 0; k < 4; ++k) {
        int i = base + k;
        unsigned long long p = (i < N) ? packed[i] : 0ULL;
        c[k] = (int)(p >> 40);
        s += c[k];
        if (i < N) {
            double deg = 1.0 + (double)(p & 0xFFFFFFFFFFULL) * (1.0 / 16777216.0);
            dis[i] = rsqrtf((float)deg + DEG_EPS);
        }
    }
    sc[t] = s; __syncthreads();
    int mySum = s;
    for (int off = 1; off < 256; off <<= 1) {
        int v = (t >= off) ? sc[t - off] : 0;
        __syncthreads();
        sc[t] += v;
        __syncthreads();
    }
    int run = sc[t] - mySum + boffs[b];
#pragma unroll
    for (int k = 0; k < 4; ++k) {
        int i = base + k;
        if (i < N) rowptr[i] = run;
        run += c[k];
    }
}

// ---------------------------------------------------------------------------
// fill CSR (blocks [0,fillB)) ∥ xw = x@W^T via MFMA (blocks [fillB, grid))
// ---------------------------------------------------------------------------
__global__ __launch_bounds__(256) void k_fill_xw(
    const int* __restrict__ rows, const int* __restrict__ cols,
    const float* __restrict__ ew, const unsigned* __restrict__ ord,
    const float* __restrict__ dis, const int* __restrict__ rowptr,
    int2* __restrict__ meta,
    const float* __restrict__ x, const float* __restrict__ W,
    unsigned short* __restrict__ xwb,
    int E, int N, int Ntiles, int fillB)
{
    const int tid = threadIdx.x;
    if ((int)blockIdx.x < fillB) {
        for (int e = blockIdx.x * 256 + tid; e < E; e += fillB * 256) {
            int r = rows[e], c = cols[e];
            float nw = ew[e] * dis[r] * dis[c];
            meta[rowptr[r] + (int)ord[e]] = make_int2(c, __float_as_int(nw));
        }
    } else {
        const int lane = tid & 63;
        const int m = lane & 15;
        const int q = lane >> 4;
        const int xwB = gridDim.x - fillB;
        const int wave = (blockIdx.x - fillB) * 4 + (tid >> 6);
        const int nwv = xwB * 4;

        // B fragments (W rows), loaded once per wave
        bf16x8 bfrag[4][2];
#pragma unroll
        for (int f = 0; f < 4; ++f)
#pragma unroll
            for (int s = 0; s < 2; ++s) {
                const float4* wp = (const float4*)(W + (f * 16 + m) * 64 + s * 32 + q * 8);
                float4 lo = wp[0], hi = wp[1];
                bf16x8 v;
                v[0] = f2bf(lo.x); v[1] = f2bf(lo.y); v[2] = f2bf(lo.z); v[3] = f2bf(lo.w);
                v[4] = f2bf(hi.x); v[5] = f2bf(hi.y); v[6] = f2bf(hi.z); v[7] = f2bf(hi.w);
                bfrag[f][s] = v;
            }

        for (int t = wave; t < Ntiles; t += nwv) {
            int n0 = t * 16;
            int nr = n0 + m; if (nr >= N) nr = N - 1;
            bf16x8 afrag[2];
#pragma unroll
            for (int s = 0; s < 2; ++s) {
                const float4* xp = (const float4*)(x + (size_t)nr * 64 + s * 32 + q * 8);
                float4 lo = xp[0], hi = xp[1];
                bf16x8 v;
                v[0] = f2bf(lo.x); v[1] = f2bf(lo.y); v[2] = f2bf(lo.z); v[3] = f2bf(lo.w);
                v[4] = f2bf(hi.x); v[5] = f2bf(hi.y); v[6] = f2bf(hi.z); v[7] = f2bf(hi.w);
                afrag[s] = v;
            }
#pragma unroll
            for (int f = 0; f < 4; ++f) {
                f32x4 acc = {0.f, 0.f, 0.f, 0.f};
                acc = __builtin_amdgcn_mfma_f32_16x16x32_bf16(afrag[0], bfrag[f][0], acc, 0, 0, 0);
                acc = __builtin_amdgcn_mfma_f32_16x16x32_bf16(afrag[1], bfrag[f][1], acc, 0, 0, 0);
#pragma unroll
                for (int r4 = 0; r4 < 4; ++r4) {
                    int node = n0 + q * 4 + r4;
                    if (node < N)
                        xwb[(size_t)node * 64 + f * 16 + m] = (unsigned short)f2bf(acc[r4]);
                }
            }
        }
    }
}

// ---------------------------------------------------------------------------
// Fused SpMM + bias + GELU + LayerNorm + residual.  One wave per row.
//   16 lanes per edge, 4 features per lane (uint2 = 4 bf16): gather load
//   instructions drop 4x vs lane-per-feature, same bytes.
// ---------------------------------------------------------------------------
__global__ __launch_bounds__(256) void k_spmm_fused(
    const int* __restrict__ rowptr, const int2* __restrict__ meta,
    const float* __restrict__ dis, const uint2* __restrict__ xw4,
    const float* __restrict__ x, const float* __restrict__ bias,
    const float* __restrict__ gamma, const float* __restrict__ beta,
    float* __restrict__ out, int N)
{
    int t = blockIdx.x * blockDim.x + threadIdx.x;
    int row = t >> 6;
    if (row >= N) return;
    const int lane = t & 63;
    const int k  = lane & 15;   // feature quad: features 4k..4k+3
    const int qh = lane >> 4;   // edge quarter 0..3

    float a0 = 0.f, a1 = 0.f, a2 = 0.f, a3 = 0.f;
    if (qh == 0) {              // self loop: xw[row]/(deg+eps), once per feature
        float s = dis[row];
        float s2 = s * s;
        uint2 v = xw4[(size_t)row * 16 + k];
        a0 = bf_lo(v.x) * s2; a1 = bf_hi(v.x) * s2;
        a2 = bf_lo(v.y) * s2; a3 = bf_hi(v.y) * s2;
    }

    int start = rowptr[row], end = rowptr[row + 1];
    for (int base = start; base < end; base += 64) {
        int rem = end - base;
        int cnt = rem < 64 ? rem : 64;
        int2 m = make_int2(0, 0);
        if (lane < cnt) m = meta[base + lane];   // 64 edges, one coalesced load
        int tmax = (cnt + 3) >> 2;               // 4 edges per step
        int tt = 0;
        for (; tt + 2 <= tmax; tt += 2) {        // 8 edges in flight
            int j0 = 4 * tt + qh, j1 = 4 * (tt + 1) + qh;
            int   c0 = __shfl(m.x, j0, 64);
            float w0 = __int_as_float(__shfl(m.y, j0, 64));
            int   c1 = __shfl(m.x, j1, 64);
            float w1 = __int_as_float(__shfl(m.y, j1, 64));
            if (j0 >= cnt) { w0 = 0.f; c0 = 0; }
            if (j1 >= cnt) { w1 = 0.f; c1 = 0; }
            uint2 v0 = xw4[(size_t)c0 * 16 + k];
            uint2 v1 = xw4[(size_t)c1 * 16 + k];
            a0 = fmaf(bf_lo(v0.x), w0, a0); a1 = fmaf(bf_hi(v0.x), w0, a1);
            a2 = fmaf(bf_lo(v0.y), w0, a2); a3 = fmaf(bf_hi(v0.y), w0, a3);
            a0 = fmaf(bf_lo(v1.x), w1, a0); a1 = fmaf(bf_hi(v1.x), w1, a1);
            a2 = fmaf(bf_lo(v1.y), w1, a2); a3 = fmaf(bf_hi(v1.y), w1, a3);
        }
        for (; tt < tmax; ++tt) {
            int j = 4 * tt + qh;
            int   c = __shfl(m.x, j, 64);
            float w = __int_as_float(__shfl(m.y, j, 64));
            if (j >= cnt) { w = 0.f; c = 0; }
            uint2 v = xw4[(size_t)c * 16 + k];
            a0 = fmaf(bf_lo(v.x), w, a0); a1 = fmaf(bf_hi(v.x), w, a1);
            a2 = fmaf(bf_lo(v.y), w, a2); a3 = fmaf(bf_hi(v.y), w, a3);
        }
    }

    // combine the 4 edge-quarters (lanes k, k+16, k+32, k+48)
#pragma unroll
    for (int mk = 16; mk < 64; mk <<= 1) {
        a0 += __shfl_xor(a0, mk, 64);
        a1 += __shfl_xor(a1, mk, 64);
        a2 += __shfl_xor(a2, mk, 64);
        a3 += __shfl_xor(a3, mk, 64);
    }

    // this lane finishes feature f = 4k + qh (all 64 features covered once)
    float a = (qh == 0) ? a0 : (qh == 1) ? a1 : (qh == 2) ? a2 : a3;
    int f = 4 * k + qh;
    a += bias[f];
    a = 0.5f * a * (1.0f + erff(a * 0.70710678118654752f));   // exact gelu

    float sum = a, ssq = a * a;
#pragma unroll
    for (int mk = 1; mk < 64; mk <<= 1) {
        sum += __shfl_xor(sum, mk, 64);
        ssq += __shfl_xor(ssq, mk, 64);
    }
    float mean = sum * (1.0f / 64.0f);
    float var  = fmaxf(ssq * (1.0f / 64.0f) - mean * mean, 0.0f);
    float rs   = rsqrtf(var + LN_EPS);
    float nrm  = (a - mean) * rs;

    // transpose so feature == lane, then coalesced store
    float nv = __shfl(nrm, ((lane & 3) << 4) | (lane >> 2), 64);
    out[(size_t)row * 64 + lane] =
        nv * gamma[lane] + beta[lane] + x[(size_t)row * 64 + lane];
}

// ---------------------------------------------------------------------------
extern "C" void kernel_launch(void* const* d_in, const int* in_sizes, int n_in,
                              void* d_out, int out_size, void* d_ws, size_t ws_size,
                              hipStream_t stream) {
    const float* x   = (const float*)d_in[0];
    const int*   ei  = (const int*)  d_in[1];   // [2,E] flat: rows then cols
    const float* ew  = (const float*)d_in[2];
    const float* W   = (const float*)d_in[3];
    const float* b   = (const float*)d_in[4];
    const float* g   = (const float*)d_in[5];
    const float* bt  = (const float*)d_in[6];
    float* out = (float*)d_out;

    const int N = in_sizes[0] / 64;
    const int E = in_sizes[1] / 2;
    const int* rows = ei;
    const int* cols = ei + E;
    const int NB = (N + 1023) / 1024;
    const int Ntiles = (N + 15) / 16;

    // ws carve-up (8-byte aligned members first)
    char* w8 = (char*)d_ws;
    unsigned long long* packed = (unsigned long long*)w8; w8 += (size_t)N * 8;
    int2*           meta = (int2*)w8;                     w8 += (size_t)E * 8;
    unsigned short* xwb  = (unsigned short*)w8;           w8 += (size_t)N * 128;
    unsigned*       ord  = (unsigned*)w8;                 w8 += (size_t)E * 4;
    float*          dis  = (float*)w8;                    w8 += (size_t)N * 4;
    int*          rowptr = (int*)w8;                      w8 += (size_t)(N + 1) * 4;
    int*          bsums  = (int*)w8;                      w8 += (size_t)NB * 4;
    int*          boffs  = (int*)w8;

    hipMemsetAsync(packed, 0, (size_t)N * 8, stream);
    k_count_deg<<<(E + 255) / 256, 256, 0, stream>>>(rows, ew, packed, ord, E);
    k_scan1<<<NB, 256, 0, stream>>>(packed, bsums, N);
    k_scan2<<<1, 256, 0, stream>>>(bsums, boffs, rowptr, NB, N);
    k_scan3<<<NB, 256, 0, stream>>>(packed, boffs, rowptr, dis, N);

    const int fillB = 1024, xwB = 256;
    k_fill_xw<<<fillB + xwB, 256, 0, stream>>>(rows, cols, ew, ord, dis, rowptr,
                                               meta, x, W, xwb, E, N, Ntiles, fillB);

    long total = (long)N * 64;
    k_spmm_fused<<<(int)((total + 255) / 256), 256, 0, stream>>>(
        rowptr, meta, dis, (const uint2*)xwb, x, b, g, bt, out, N);
}